// Round 14
// baseline (1309.430 us; speedup 1.0000x reference)
//
#include <hip/hip_runtime.h>
#include <math.h>

#define H 128
typedef unsigned short u16;
typedef unsigned char u8;
typedef unsigned int u32;
typedef _Float16 f16;
typedef f16 f16x8 __attribute__((ext_vector_type(8)));
typedef float f32x4 __attribute__((ext_vector_type(4)));
typedef float f32x2 __attribute__((ext_vector_type(2)));

#if __has_builtin(__builtin_amdgcn_cvt_pk_fp8_f32)
#define HW8 1
#else
#define HW8 0
#endif

static inline int cdiv(long long a, long long b) { return (int)((a + b - 1) / b); }

// ---------------- fp8 e4m3fn software codec (fallback) ----------------
struct F8 {
    static __device__ inline float dec(u8 v) {
        int e = (v >> 3) & 15, m = v & 7;
        float f = (e == 0) ? (float)m * 0.001953125f : ldexpf(1.f + 0.125f * (float)m, e - 7);
        return (v & 0x80) ? -f : f;
    }
    static __device__ inline u8 enc(float x) {
        u8 s = (u8)((__float_as_uint(x) >> 24) & 0x80);
        float ax = fabsf(x);
        if (!(ax < 448.f)) return s | 0x7E;
        if (ax < 0.015625f) {
            int m = (int)rintf(ax * 512.f);
            if (m >= 8) return s | 0x08;
            return s | (u8)m;
        }
        int e; float fr = frexpf(ax, &e);
        int E = e - 1;
        int m = (int)rintf(fr * 16.f - 8.f);
        if (m == 8) { m = 0; ++E; }
        if (E > 8) return s | 0x7E;
        return s | (u8)(((E + 7) << 3) | m);
    }
};

static __device__ inline u32 enc4(float x0, float x1, float x2, float x3) {
#if HW8
    u32 w = __builtin_amdgcn_cvt_pk_fp8_f32(x0, x1, 0, false);
    w = __builtin_amdgcn_cvt_pk_fp8_f32(x2, x3, w, true);
    return w;
#else
    union { u8 b[4]; u32 u; } p;
    p.b[0] = F8::enc(x0); p.b[1] = F8::enc(x1); p.b[2] = F8::enc(x2); p.b[3] = F8::enc(x3);
    return p.u;
#endif
}
static __device__ inline float4 dec4(u32 v) {
#if HW8
    f32x2 lo = __builtin_amdgcn_cvt_pk_f32_fp8(v, false);
    f32x2 hi = __builtin_amdgcn_cvt_pk_f32_fp8(v, true);
    return make_float4(lo.x, lo.y, hi.x, hi.y);
#else
    union { u32 u; u8 b[4]; } c; c.u = v;
    return make_float4(F8::dec(c.b[0]), F8::dec(c.b[1]), F8::dec(c.b[2]), F8::dec(c.b[3]));
#endif
}
static __device__ inline float dec1(u8 b) {
#if HW8
    return __builtin_amdgcn_cvt_f32_fp8((int)b, 0);
#else
    return F8::dec(b);
#endif
}

// ---------------- fused degree histograms (both graphs) ----------------
__global__ __launch_bounds__(256) void hist_all_k(const int* __restrict__ src, const int* __restrict__ dst,
                                                  const int* __restrict__ lsrc, const int* __restrict__ ldst,
                                                  int* __restrict__ con, int* __restrict__ cin,
                                                  int* __restrict__ coe, int* __restrict__ cie,
                                                  int E, int E2) {
    int i = blockIdx.x * 256 + threadIdx.x;
    if (i < E) {
        atomicAdd(&con[src[i]], 1);
        atomicAdd(&cin[dst[i]], 1);
    } else if (i < E + E2) {
        int j = i - E;
        atomicAdd(&coe[lsrc[j]], 1);
        atomicAdd(&cie[ldst[j]], 1);
    }
}

// ---------------- fused rs (all 4 arrays) + pairE = (roe*d, roe) ----------------
__global__ __launch_bounds__(256) void rs_all_k(const int* __restrict__ con, const int* __restrict__ cin,
                                                const int* __restrict__ coe, const int* __restrict__ cie,
                                                float* __restrict__ ron, float* __restrict__ rin,
                                                float* __restrict__ roe, float* __restrict__ rie,
                                                const float* __restrict__ d, float2* __restrict__ pairE,
                                                int N, int E) {
    int i = blockIdx.x * 256 + threadIdx.x;
    if (i < N) { int v = con[i]; ron[i] = rsqrtf((float)(v < 1 ? 1 : v)); }
    else if (i < 2 * N) { int n = i - N; int v = cin[n]; rin[n] = rsqrtf((float)(v < 1 ? 1 : v)); }
    else if (i < 2 * N + E) {
        int n = i - 2 * N; int v = coe[n];
        float r = rsqrtf((float)(v < 1 ? 1 : v));
        roe[n] = r;
        pairE[n] = make_float2(r * d[n], r);
    } else if (i < 2 * N + 2 * E) { int n = i - 2 * N - E; int v = cie[n]; rie[n] = rsqrtf((float)(v < 1 ? 1 : v)); }
}

// ---------------- segment counts of SORTED id arrays (both) ----------------
__global__ __launch_bounds__(128) void seg2_k(const int* __restrict__ seg0, int n0,
                                              const int* __restrict__ seg1, int n1,
                                              int B, int* __restrict__ cnt0, int* __restrict__ cnt1) {
    const int* seg = blockIdx.x ? seg1 : seg0;
    int n = blockIdx.x ? n1 : n0;
    int* cnt = blockIdx.x ? cnt1 : cnt0;
    __shared__ int bound[129];
    int b = threadIdx.x;
    if (b <= B) {
        int lo = 0, hi = n;
        while (lo < hi) {
            int mid = (lo + hi) >> 1;
            if (seg[mid] < b) lo = mid + 1; else hi = mid;
        }
        bound[b] = lo;
    }
    __syncthreads();
    if (b < B) cnt[b] = bound[b + 1] - bound[b];
}

// ---------------- scan (exclusive), both arrays in one grid ----------------
__global__ __launch_bounds__(256) void scan_block2_k(const int* __restrict__ inA, int* __restrict__ outA, int nA, int nbA,
                                                     const int* __restrict__ inB, int* __restrict__ outB, int nB,
                                                     int* __restrict__ bsum) {
    __shared__ int sh[256];
    const int* in; int* out; int n; int gid; int bs;
    if ((int)blockIdx.x < nbA) { in = inA; out = outA; n = nA; gid = blockIdx.x * 256 + threadIdx.x; bs = blockIdx.x; }
    else { in = inB; out = outB; n = nB; gid = (blockIdx.x - nbA) * 256 + threadIdx.x; bs = blockIdx.x; }
    int v = (gid < n) ? in[gid] : 0;
    sh[threadIdx.x] = v;
    __syncthreads();
    for (int off = 1; off < 256; off <<= 1) {
        int t = (threadIdx.x >= off) ? sh[threadIdx.x - off] : 0;
        __syncthreads();
        sh[threadIdx.x] += t;
        __syncthreads();
    }
    if (gid < n) out[gid] = sh[threadIdx.x] - v;
    if (threadIdx.x == 255) bsum[bs] = sh[255];
}

__global__ __launch_bounds__(256) void scan_bsum2_k(int* __restrict__ bsum, int nbA, int nbB) {
    __shared__ int sh[256];
    __shared__ int carry;
#pragma unroll 1
    for (int part = 0; part < 2; ++part) {
        int base0 = part ? nbA : 0;
        int nb = part ? nbB : nbA;
        if (threadIdx.x == 0) carry = 0;
        __syncthreads();
        for (int base = 0; base < nb; base += 256) {
            int i = base + threadIdx.x;
            int v = (i < nb) ? bsum[base0 + i] : 0;
            sh[threadIdx.x] = v;
            __syncthreads();
            for (int off = 1; off < 256; off <<= 1) {
                int t = (threadIdx.x >= off) ? sh[threadIdx.x - off] : 0;
                __syncthreads();
                sh[threadIdx.x] += t;
                __syncthreads();
            }
            if (i < nb) bsum[base0 + i] = sh[threadIdx.x] - v + carry;
            __syncthreads();
            if (threadIdx.x == 0) carry += sh[255];
            __syncthreads();
        }
    }
}

__global__ __launch_bounds__(256) void scan_add2_k(int* __restrict__ offsA, int* __restrict__ curA, int nA, int nbA, int nnzA,
                                                   int* __restrict__ offsB, int* __restrict__ curB, int nB, int nnzB,
                                                   const int* __restrict__ bsum) {
    int* offs; int* curp; int n; int gid; int bs; int nnz;
    if ((int)blockIdx.x < nbA) { offs = offsA; curp = curA; n = nA; gid = blockIdx.x * 256 + threadIdx.x; bs = blockIdx.x; nnz = nnzA; }
    else { offs = offsB; curp = curB; n = nB; gid = (blockIdx.x - nbA) * 256 + threadIdx.x; bs = blockIdx.x; nnz = nnzB; }
    if (gid < n) {
        int v = offs[gid] + bsum[bs];
        offs[gid] = v;
        curp[gid] = v;
    }
    if (gid == 0) offs[n] = nnz;
}

// ---------------- CSR fill (both graphs): slot gets (src, dst) pair ----------------
__global__ __launch_bounds__(256) void fill2_k(const int* __restrict__ src, const int* __restrict__ dst,
                                               const int* __restrict__ lsrc, const int* __restrict__ ldst,
                                               int* __restrict__ cur_n, int* __restrict__ cur_e,
                                               uint2* __restrict__ nbr_n, uint2* __restrict__ nbr_e,
                                               int E, int E2) {
    int i = blockIdx.x * 256 + threadIdx.x;
    if (i < E) {
        int dd = dst[i];
        int p = atomicAdd(&cur_n[dd], 1);
        nbr_n[p] = make_uint2((u32)src[i], (u32)dd);
    } else if (i < E + E2) {
        int j = i - E;
        int dd = ldst[j];
        int p = atomicAdd(&cur_e[dd], 1);
        nbr_e[p] = make_uint2((u32)lsrc[j], (u32)dd);
    }
}

// ---------------- weight prep (all 6): Wt[n][k] = (f16) W[k][n] ----------------
__global__ __launch_bounds__(256) void prep_w_all_k(const float* __restrict__ gW, const float* __restrict__ lgW,
                                                    f16* __restrict__ wt, int L) {
    int mat = blockIdx.x >> 6;
    int idx = (blockIdx.x & 63) * 256 + threadIdx.x;
    int k = idx >> 7, n = idx & 127;
    const float* W = (mat < L) ? gW + (size_t)mat * H * H : lgW + (size_t)(mat - L) * H * H;
    wt[(size_t)mat * H * H + (size_t)n * H + k] = (f16)W[(size_t)k * H + n];
}

// ---------------- node feature init (fp8, pre-scaled by rs_out) ----------------
__global__ __launch_bounds__(256) void init_node_k(const int* __restrict__ z, const float* __restrict__ emb,
                                                   const float* __restrict__ ron, u8* __restrict__ featN, int N) {
    int idx = blockIdx.x * 256 + threadIdx.x;
    if (idx >= N * 32) return;
    int n = idx >> 5, c4 = (idx & 31) << 2;
    float sc = ron[n];
    const float4 v = *(const float4*)(emb + (size_t)z[n] * H + c4);
    *(u32*)(featN + (size_t)n * H + c4) = enc4(v.x * sc, v.y * sc, v.z * sc, v.w * sc);
}

// ---------------- MFMA phase with LDS-staged, full-line output stores ----------------
// After A-frags are in registers the wave's As slice is dead -> reuse as fp8 staging.
// Final stores: 4 lanes cover one full 128B row (2x uint4 per lane) => every 64B line is
// fully covered by one instruction => no write-allocate RMW fetches (the FETCH~WRITE smoking
// gun in round-13's l0 dispatch).
__device__ __forceinline__ void conv_mfma_phase(
    u8* __restrict__ Xout, const f16* __restrict__ Wt, const float* __restrict__ bias,
    const float* __restrict__ scale_out, int M, int row0, f16 (*As)[136], int wave, int lane) {
    const int rowbase = row0 + wave * 16;
    if (rowbase >= M) return;
    const int l15 = lane & 15;
    const int quad = lane >> 4;

    f16x8 a[4];
#pragma unroll
    for (int kt = 0; kt < 4; ++kt)
        a[kt] = *(const f16x8*)&As[wave * 16 + l15][kt * 32 + quad * 8];

    float rsc[4];
#pragma unroll
    for (int r = 0; r < 4; ++r) {
        int gr = rowbase + quad * 4 + r;
        rsc[r] = (scale_out && gr < M) ? scale_out[gr] : 1.f;
    }

    u8* stage = (u8*)&As[wave * 16][0];   // wave-private slice, 4352B >= 16*128 staging

#pragma unroll
    for (int n0 = 0; n0 < 8; ++n0) {
        f32x4 acc = {0.f, 0.f, 0.f, 0.f};
        const f16* bp = Wt + (size_t)(n0 * 16 + l15) * H + quad * 8;
#pragma unroll
        for (int kt = 0; kt < 4; ++kt) {
            f16x8 b = *(const f16x8*)(bp + kt * 32);
            acc = __builtin_amdgcn_mfma_f32_16x16x32_f16(a[kt], b, acc, 0, 0, 0);
        }
        int col = n0 * 16 + l15;
        float bv = bias[col];
        float o[4];
#pragma unroll
        for (int r = 0; r < 4; ++r) o[r] = fmaxf(acc[r] + bv, 0.f) * rsc[r];
        u32 w = enc4(o[0], o[1], o[2], o[3]);
#pragma unroll
        for (int r = 0; r < 4; ++r) stage[(quad * 4 + r) * 128 + col] = (u8)(w >> (8 * r));
    }
    // same-wave LDS RAW: compiler inserts lgkmcnt wait
    const int lr = lane >> 2;           // local row 0..15
    const int lc = (lane & 3) * 32;     // col base: 4 lanes cover the 128B row
    int gr = rowbase + lr;
    if (gr < M) {
        uint4 v0 = *(const uint4*)&stage[lr * 128 + lc];
        uint4 v1 = *(const uint4*)&stage[lr * 128 + lc + 16];
        *(uint4*)(Xout + (size_t)gr * H + lc) = v0;
        *(uint4*)(Xout + (size_t)gr * H + lc + 16) = v1;
    }
}

__device__ __forceinline__ void conv_wave(
    const u8* __restrict__ Xin, u8* __restrict__ Xout,
    const int* __restrict__ offs, const uint2* __restrict__ nbr2,
    const float* __restrict__ rs_in, const f16* __restrict__ Wt,
    const float* __restrict__ bias, const float* __restrict__ scale_out, int M,
    int row0, f16 (*As)[136], int wave, int lane) {
    const int rowbase = row0 + wave * 16;     // wave-private 16 rows

    // zero this wave's As slice
    {
        uint2* zp = (uint2*)&As[wave * 16][0];
#pragma unroll
        for (int i = 0; i < 9; ++i) {
            int o = lane + i * 64;
            if (o < 544) zp[o] = make_uint2(0u, 0u);
        }
    }

    // ---- gather (wave-private) ----
    {
        const int gl = lane >> 4;
        const int ln = lane & 15;
        const int r_lo = min(rowbase + gl * 4, M);
        const int r_hi = min(rowbase + gl * 4 + 4, M);
        const int jbeg = offs[r_lo];
        const int jend = offs[r_hi];
        if (jbeg < jend) {
            float a0 = 0.f, a1 = 0.f, a2 = 0.f, a3 = 0.f, a4 = 0.f, a5 = 0.f, a6 = 0.f, a7 = 0.f;
            int curdst = -1;
            for (int j = jbeg; j < jend; j += 4) {
                int j1 = min(j + 1, jend - 1), j2 = min(j + 2, jend - 1), j3 = min(j + 3, jend - 1);
                uint2 e0 = nbr2[j], e1 = nbr2[j1], e2 = nbr2[j2], e3 = nbr2[j3];
                uint2 f0 = *(const uint2*)(Xin + ((size_t)e0.x << 7) + (ln << 3));
                uint2 f1 = *(const uint2*)(Xin + ((size_t)e1.x << 7) + (ln << 3));
                uint2 f2 = *(const uint2*)(Xin + ((size_t)e2.x << 7) + (ln << 3));
                uint2 f3 = *(const uint2*)(Xin + ((size_t)e3.x << 7) + (ln << 3));
                uint2 ev[4] = {e0, e1, e2, e3};
                uint2 fv[4] = {f0, f1, f2, f3};
#pragma unroll
                for (int k = 0; k < 4; ++k) {
                    if (j + k < jend) {
                        int dk = (int)ev[k].y;
                        if (dk != curdst) {
                            if (curdst >= 0) {
                                float ri = rs_in[curdst];
                                f16x8 o;
                                o[0] = (f16)(a0 * ri); o[1] = (f16)(a1 * ri);
                                o[2] = (f16)(a2 * ri); o[3] = (f16)(a3 * ri);
                                o[4] = (f16)(a4 * ri); o[5] = (f16)(a5 * ri);
                                o[6] = (f16)(a6 * ri); o[7] = (f16)(a7 * ri);
                                *(f16x8*)&As[curdst - row0][ln << 3] = o;
                                a0 = a1 = a2 = a3 = a4 = a5 = a6 = a7 = 0.f;
                            }
                            curdst = dk;
                        }
                        float4 lo = dec4(fv[k].x);
                        float4 hi = dec4(fv[k].y);
                        a0 += lo.x; a1 += lo.y; a2 += lo.z; a3 += lo.w;
                        a4 += hi.x; a5 += hi.y; a6 += hi.z; a7 += hi.w;
                    }
                }
            }
            if (curdst >= 0) {
                float ri = rs_in[curdst];
                f16x8 o;
                o[0] = (f16)(a0 * ri); o[1] = (f16)(a1 * ri);
                o[2] = (f16)(a2 * ri); o[3] = (f16)(a3 * ri);
                o[4] = (f16)(a4 * ri); o[5] = (f16)(a5 * ri);
                o[6] = (f16)(a6 * ri); o[7] = (f16)(a7 * ri);
                *(f16x8*)&As[curdst - row0][ln << 3] = o;
            }
        }
    }
    // no __syncthreads: As slice is wave-private

    conv_mfma_phase(Xout, Wt, bias, scale_out, M, row0, As, wave, lane);
}

// ---------------- layer-0 line conv wave: rank-1 features -> 8B scalar gather ----------------
__device__ __forceinline__ void conv_wave_l0e(
    u8* __restrict__ Xout, const int* __restrict__ offs, const uint2* __restrict__ nbr2,
    const float2* __restrict__ pairE, const float* __restrict__ rs_in,
    const float* __restrict__ epw, const float* __restrict__ epb,
    const f16* __restrict__ Wt, const float* __restrict__ bias,
    const float* __restrict__ scale_out, int E,
    int row0, f16 (*As)[136], int wave, int lane) {
    const int rowbase = row0 + wave * 16;
    const int r = lane >> 2;            // row 0..15, 4 lanes per row
    const int t = lane & 3;
    int grow = min(rowbase + r, E - 1);
    int jb = offs[grow], je = offs[grow + 1];
    float sd = 0.f, sw = 0.f;
    for (int j = jb + t; j < je; j += 4) {
        float2 p = pairE[nbr2[j].x];
        sd += p.x; sw += p.y;
    }
    sd += __shfl_xor(sd, 1); sw += __shfl_xor(sw, 1);
    sd += __shfl_xor(sd, 2); sw += __shfl_xor(sw, 2);
    float ri = (rowbase + r < E) ? rs_in[rowbase + r] : 0.f;
    sd *= ri; sw *= ri;
#pragma unroll
    for (int c8 = 0; c8 < 4; ++c8) {
        int c0 = t * 32 + c8 * 8;
        const float4 wa = *(const float4*)(epw + c0);
        const float4 wb = *(const float4*)(epw + c0 + 4);
        const float4 ba = *(const float4*)(epb + c0);
        const float4 bb = *(const float4*)(epb + c0 + 4);
        f16x8 o;
        o[0] = (f16)(sd * wa.x + sw * ba.x); o[1] = (f16)(sd * wa.y + sw * ba.y);
        o[2] = (f16)(sd * wa.z + sw * ba.z); o[3] = (f16)(sd * wa.w + sw * ba.w);
        o[4] = (f16)(sd * wb.x + sw * bb.x); o[5] = (f16)(sd * wb.y + sw * bb.y);
        o[6] = (f16)(sd * wb.z + sw * bb.z); o[7] = (f16)(sd * wb.w + sw * bb.w);
        *(f16x8*)&As[wave * 16 + r][c0] = o;
    }
    conv_mfma_phase(Xout, Wt, bias, scale_out, E, row0, As, wave, lane);
}

// ---------------- combined conv (layers 1,2): node ++ line in one dispatch ----------------
__global__ __launch_bounds__(256) void conv2_k(
    const u8* __restrict__ XinN, u8* __restrict__ XoutN,
    const int* __restrict__ offs_n, const uint2* __restrict__ nbr_n,
    const float* __restrict__ rinN, const f16* __restrict__ WtN,
    const float* __restrict__ biasN, const float* __restrict__ scaleN, int N, int nbCN,
    const u8* __restrict__ XinE, u8* __restrict__ XoutE,
    const int* __restrict__ offs_e, const uint2* __restrict__ nbr_e,
    const float* __restrict__ rinE, const f16* __restrict__ WtE,
    const float* __restrict__ biasE, const float* __restrict__ scaleE, int E) {
    __shared__ f16 As[64][136];
    const int tid = threadIdx.x;
    const int wave = tid >> 6;
    const int lane = tid & 63;
    if ((int)blockIdx.x < nbCN) {
        conv_wave(XinN, XoutN, offs_n, nbr_n, rinN, WtN, biasN, scaleN, N,
                  blockIdx.x * 64, As, wave, lane);
    } else {
        conv_wave(XinE, XoutE, offs_e, nbr_e, rinE, WtE, biasE, scaleE, E,
                  (blockIdx.x - nbCN) * 64, As, wave, lane);
    }
}

// ---------------- combined conv layer 0: node standard ++ line rank-1 ----------------
__global__ __launch_bounds__(256) void conv2_l0_k(
    const u8* __restrict__ XinN, u8* __restrict__ XoutN,
    const int* __restrict__ offs_n, const uint2* __restrict__ nbr_n,
    const float* __restrict__ rinN, const f16* __restrict__ WtN,
    const float* __restrict__ biasN, const float* __restrict__ scaleN, int N, int nbCN,
    u8* __restrict__ XoutE,
    const int* __restrict__ offs_e, const uint2* __restrict__ nbr_e,
    const float2* __restrict__ pairE, const float* __restrict__ rinE,
    const float* __restrict__ epw, const float* __restrict__ epb,
    const f16* __restrict__ WtE, const float* __restrict__ biasE,
    const float* __restrict__ scaleE, int E) {
    __shared__ f16 As[64][136];
    const int tid = threadIdx.x;
    const int wave = tid >> 6;
    const int lane = tid & 63;
    if ((int)blockIdx.x < nbCN) {
        conv_wave(XinN, XoutN, offs_n, nbr_n, rinN, WtN, biasN, scaleN, N,
                  blockIdx.x * 64, As, wave, lane);
    } else {
        conv_wave_l0e(XoutE, offs_e, nbr_e, pairE, rinE, epw, epb, WtE, biasE, scaleE, E,
                      (blockIdx.x - nbCN) * 64, As, wave, lane);
    }
}

// ---------------- segment-sum pooling, both graphs in one dispatch ----------------
__device__ __forceinline__ void pool_chunk(const u8* __restrict__ X, const int* __restrict__ seg,
                                           float* __restrict__ out_sum, int M, int blk, int j) {
    const int chunk = blk * 256;
    const int end = min(chunk + 256, M);
    float acc = 0.f;
    int g_cur = -1;
    for (int r = chunk; r < end; ++r) {
        int g = seg[r];
        if (g != g_cur) {
            if (g_cur >= 0) atomicAdd(&out_sum[(size_t)g_cur * H + j], acc);
            acc = 0.f;
            g_cur = g;
        }
        acc += dec1(X[(size_t)r * H + j]);
    }
    if (g_cur >= 0) atomicAdd(&out_sum[(size_t)g_cur * H + j], acc);
}

__global__ __launch_bounds__(128) void pool_both_k(const u8* __restrict__ XN, const int* __restrict__ ng,
                                                   float* __restrict__ hg, int N, int nbPN,
                                                   const u8* __restrict__ XE, const int* __restrict__ eg,
                                                   float* __restrict__ he, int E) {
    if ((int)blockIdx.x < nbPN) pool_chunk(XN, ng, hg, N, blockIdx.x, threadIdx.x);
    else pool_chunk(XE, eg, he, E, blockIdx.x - nbPN, threadIdx.x);
}

// ---------------- readout MLP ----------------
__global__ __launch_bounds__(128) void readout_k(const float* __restrict__ hg, const float* __restrict__ he,
                                                 const int* __restrict__ cn, const int* __restrict__ ce,
                                                 const float* __restrict__ r1w, const float* __restrict__ r1b,
                                                 const float* __restrict__ r2w, const float* __restrict__ r2b,
                                                 float* __restrict__ out) {
    const int b = blockIdx.x;
    const int j = threadIdx.x;
    const float invn = 1.f / fmaxf((float)cn[b], 1.f);
    const float inve = 1.f / fmaxf((float)ce[b], 1.f);
    float acc = r1b[j];
    for (int k = 0; k < H; ++k) acc = fmaf(hg[(size_t)b * H + k] * invn, r1w[(size_t)k * H + j], acc);
    for (int k = 0; k < H; ++k) acc = fmaf(he[(size_t)b * H + k] * inve, r1w[(size_t)(k + H) * H + j], acc);
    float s = acc / (1.f + expf(-acc));
    __shared__ float red[128];
    red[j] = s * r2w[j];
    __syncthreads();
    for (int off = 64; off > 0; off >>= 1) {
        if (j < off) red[j] += red[j + off];
        __syncthreads();
    }
    if (j == 0) out[b] = red[0] + r2b[0];
}

// diagnostic
__global__ void report_k(float* out, int n, float val) {
    int i = blockIdx.x * 64 + threadIdx.x;
    if (i < n) out[i] = val;
}

extern "C" void kernel_launch(void* const* d_in, const int* in_sizes, int n_in,
                              void* d_out, int out_size, void* d_ws, size_t ws_size,
                              hipStream_t stream) {
    const int* z          = (const int*)d_in[0];
    const float* d        = (const float*)d_in[1];
    const int* src        = (const int*)d_in[2];
    const int* dst        = (const int*)d_in[3];
    const int* lsrc       = (const int*)d_in[4];
    const int* ldst       = (const int*)d_in[5];
    const int* node_graph = (const int*)d_in[6];
    const int* edge_graph = (const int*)d_in[7];
    const float* emb      = (const float*)d_in[8];
    const float* epw      = (const float*)d_in[9];
    const float* epb      = (const float*)d_in[10];
    const float* gW       = (const float*)d_in[11];
    const float* gb       = (const float*)d_in[12];
    const float* lgW      = (const float*)d_in[13];
    const float* lgb      = (const float*)d_in[14];
    const float* r1w      = (const float*)d_in[15];
    const float* r1b      = (const float*)d_in[16];
    const float* r2w      = (const float*)d_in[17];
    const float* r2b      = (const float*)d_in[18];

    const int N  = in_sizes[0];
    const int E  = in_sizes[2];
    const int E2 = in_sizes[4];
    const int B  = out_size;
    const int L  = 3;
    float* out = (float*)d_out;
    char* ws = (char*)d_ws;

    // ---- workspace (~219 MB; budget 268 MB) ----
    size_t off = 0;
    auto al = [&](size_t b) -> char* { char* q = ws + off; off += (b + 255) & ~(size_t)255; return q; };
    u8*  featEA = (u8*)al((size_t)E * H);
    u8*  featEB = (u8*)al((size_t)E * H);
    u8*  featNA = (u8*)al((size_t)N * H);
    u8*  featNB = (u8*)al((size_t)N * H);
    f16* wt    = (f16*)al((size_t)2 * L * H * H * 2);
    float* ron = (float*)al((size_t)N * 4);
    float* rin = (float*)al((size_t)N * 4);
    float* roe = (float*)al((size_t)E * 4);
    float* rie = (float*)al((size_t)E * 4);
    float2* pairE = (float2*)al((size_t)E * 8);
    size_t cntCount = (size_t)2 * N + 2 * E + 2 * B;
    int* cnts = (int*)al(cntCount * 4);
    size_t cntBytes = ((size_t)2 * N + 2 * E) * 4;
    int* con = cnts; int* cin_ = con + N; int* coe = cin_ + N; int* cie = coe + E;
    int* cntn = cie + E; int* cnte = cntn + B;
    int* offs_n = (int*)al(((size_t)N + 1) * 4);
    int* cur_n  = (int*)al((size_t)N * 4);
    int* offs_e = (int*)al(((size_t)E + 1) * 4);
    int* cur_e  = (int*)al((size_t)E * 4);
    uint2* nbr_n = (uint2*)al((size_t)E * 8);
    uint2* nbr_e = (uint2*)al((size_t)E2 * 8);
    int nbN = cdiv(N, 256), nbE = cdiv(E, 256);
    int* bsum   = (int*)al(((size_t)nbN + nbE + 2) * 4);
    float* pools = (float*)al((size_t)2 * B * H * 4);
    float* hg = pools;
    float* he = pools + (size_t)B * H;

    if (off > ws_size) {
        report_k<<<cdiv(B, 64), 64, 0, stream>>>(out, B, (float)(ws_size >> 20));
        return;
    }

    hipMemsetAsync(cnts, 0, cntBytes, stream);
    hipMemsetAsync(pools, 0, (size_t)2 * B * H * 4, stream);

    // setup (fused)
    prep_w_all_k<<<2 * L * 64, 256, 0, stream>>>(gW, lgW, wt, L);
    hist_all_k<<<cdiv((long long)E + E2, 256), 256, 0, stream>>>(src, dst, lsrc, ldst, con, cin_, coe, cie, E, E2);
    seg2_k<<<2, 128, 0, stream>>>(node_graph, N, edge_graph, E, B, cntn, cnte);
    rs_all_k<<<cdiv((long long)2 * N + 2 * E, 256), 256, 0, stream>>>(con, cin_, coe, cie, ron, rin, roe, rie,
                                                                     d, pairE, N, E);

    // CSR build (both graphs)
    scan_block2_k<<<nbN + nbE, 256, 0, stream>>>(cin_, offs_n, N, nbN, cie, offs_e, E, bsum);
    scan_bsum2_k<<<1, 256, 0, stream>>>(bsum, nbN, nbE);
    scan_add2_k<<<nbN + nbE, 256, 0, stream>>>(offs_n, cur_n, N, nbN, E, offs_e, cur_e, E, E2, bsum);
    fill2_k<<<cdiv((long long)E + E2, 256), 256, 0, stream>>>(src, dst, lsrc, ldst, cur_n, cur_e, nbr_n, nbr_e, E, E2);

    // node feature init only
    init_node_k<<<cdiv((long long)N * 32, 256), 256, 0, stream>>>(z, emb, ron, featNA, N);

    const int nbCN = cdiv(N, 64), nbCE = cdiv(E, 64);

    // layer 0: node standard ++ line rank-1
    conv2_l0_k<<<nbCN + nbCE, 256, 0, stream>>>(
        featNA, featNB, offs_n, nbr_n, rin, wt, gb, ron, N, nbCN,
        featEB, offs_e, nbr_e, pairE, rie, epw, epb,
        wt + (size_t)L * H * H, lgb, roe, E);

    // layers 1..L-1
    u8* curN = featNB; u8* curE = featEB;
    for (int l = 1; l < L; ++l) {
        u8* nxtN = (curN == featNA) ? featNB : featNA;
        u8* nxtE = (curE == featEA) ? featEB : featEA;
        conv2_k<<<nbCN + nbCE, 256, 0, stream>>>(
            curN, nxtN, offs_n, nbr_n, rin, wt + (size_t)l * H * H, gb + (size_t)l * H,
            (l < L - 1) ? ron : nullptr, N, nbCN,
            curE, nxtE, offs_e, nbr_e, rie, wt + (size_t)(L + l) * H * H, lgb + (size_t)l * H,
            (l < L - 1) ? roe : nullptr, E);
        curN = nxtN; curE = nxtE;
    }

    // pooling, both graphs
    const int nbPN = cdiv(N, 256);
    pool_both_k<<<nbPN + cdiv(E, 256), 128, 0, stream>>>(curN, node_graph, hg, N, nbPN,
                                                         curE, edge_graph, he, E);

    readout_k<<<B, 128, 0, stream>>>(hg, he, cntn, cnte, r1w, r1b, r2w, r2b, out);
}

// Round 15
// 1216.701 us; speedup vs baseline: 1.0762x; 1.0762x over previous
//
#include <hip/hip_runtime.h>
#include <math.h>

#define H 128
typedef unsigned short u16;
typedef unsigned char u8;
typedef unsigned int u32;
typedef _Float16 f16;
typedef f16 f16x8 __attribute__((ext_vector_type(8)));
typedef float f32x4 __attribute__((ext_vector_type(4)));
typedef float f32x2 __attribute__((ext_vector_type(2)));

#if __has_builtin(__builtin_amdgcn_cvt_pk_fp8_f32)
#define HW8 1
#else
#define HW8 0
#endif

#define SSTRIDE 144   // fp8 staging row stride: 36 dwords -> 4-bank rotation/row, 16B-aligned

static inline int cdiv(long long a, long long b) { return (int)((a + b - 1) / b); }

// ---------------- fp8 e4m3fn software codec (fallback) ----------------
struct F8 {
    static __device__ inline float dec(u8 v) {
        int e = (v >> 3) & 15, m = v & 7;
        float f = (e == 0) ? (float)m * 0.001953125f : ldexpf(1.f + 0.125f * (float)m, e - 7);
        return (v & 0x80) ? -f : f;
    }
    static __device__ inline u8 enc(float x) {
        u8 s = (u8)((__float_as_uint(x) >> 24) & 0x80);
        float ax = fabsf(x);
        if (!(ax < 448.f)) return s | 0x7E;
        if (ax < 0.015625f) {
            int m = (int)rintf(ax * 512.f);
            if (m >= 8) return s | 0x08;
            return s | (u8)m;
        }
        int e; float fr = frexpf(ax, &e);
        int E = e - 1;
        int m = (int)rintf(fr * 16.f - 8.f);
        if (m == 8) { m = 0; ++E; }
        if (E > 8) return s | 0x7E;
        return s | (u8)(((E + 7) << 3) | m);
    }
};

static __device__ inline u32 enc4(float x0, float x1, float x2, float x3) {
#if HW8
    u32 w = __builtin_amdgcn_cvt_pk_fp8_f32(x0, x1, 0, false);
    w = __builtin_amdgcn_cvt_pk_fp8_f32(x2, x3, w, true);
    return w;
#else
    union { u8 b[4]; u32 u; } p;
    p.b[0] = F8::enc(x0); p.b[1] = F8::enc(x1); p.b[2] = F8::enc(x2); p.b[3] = F8::enc(x3);
    return p.u;
#endif
}
static __device__ inline float4 dec4(u32 v) {
#if HW8
    f32x2 lo = __builtin_amdgcn_cvt_pk_f32_fp8(v, false);
    f32x2 hi = __builtin_amdgcn_cvt_pk_f32_fp8(v, true);
    return make_float4(lo.x, lo.y, hi.x, hi.y);
#else
    union { u32 u; u8 b[4]; } c; c.u = v;
    return make_float4(F8::dec(c.b[0]), F8::dec(c.b[1]), F8::dec(c.b[2]), F8::dec(c.b[3]));
#endif
}
static __device__ inline float dec1(u8 b) {
#if HW8
    return __builtin_amdgcn_cvt_f32_fp8((int)b, 0);
#else
    return F8::dec(b);
#endif
}

// ---------------- fused degree histograms (both graphs) ----------------
__global__ __launch_bounds__(256) void hist_all_k(const int* __restrict__ src, const int* __restrict__ dst,
                                                  const int* __restrict__ lsrc, const int* __restrict__ ldst,
                                                  int* __restrict__ con, int* __restrict__ cin,
                                                  int* __restrict__ coe, int* __restrict__ cie,
                                                  int E, int E2) {
    int i = blockIdx.x * 256 + threadIdx.x;
    if (i < E) {
        atomicAdd(&con[src[i]], 1);
        atomicAdd(&cin[dst[i]], 1);
    } else if (i < E + E2) {
        int j = i - E;
        atomicAdd(&coe[lsrc[j]], 1);
        atomicAdd(&cie[ldst[j]], 1);
    }
}

// ---------------- fused rs (all 4 arrays) + pairE = (roe*d, roe) ----------------
__global__ __launch_bounds__(256) void rs_all_k(const int* __restrict__ con, const int* __restrict__ cin,
                                                const int* __restrict__ coe, const int* __restrict__ cie,
                                                float* __restrict__ ron, float* __restrict__ rin,
                                                float* __restrict__ roe, float* __restrict__ rie,
                                                const float* __restrict__ d, float2* __restrict__ pairE,
                                                int N, int E) {
    int i = blockIdx.x * 256 + threadIdx.x;
    if (i < N) { int v = con[i]; ron[i] = rsqrtf((float)(v < 1 ? 1 : v)); }
    else if (i < 2 * N) { int n = i - N; int v = cin[n]; rin[n] = rsqrtf((float)(v < 1 ? 1 : v)); }
    else if (i < 2 * N + E) {
        int n = i - 2 * N; int v = coe[n];
        float r = rsqrtf((float)(v < 1 ? 1 : v));
        roe[n] = r;
        pairE[n] = make_float2(r * d[n], r);
    } else if (i < 2 * N + 2 * E) { int n = i - 2 * N - E; int v = cie[n]; rie[n] = rsqrtf((float)(v < 1 ? 1 : v)); }
}

// ---------------- segment counts of SORTED id arrays (both) ----------------
__global__ __launch_bounds__(128) void seg2_k(const int* __restrict__ seg0, int n0,
                                              const int* __restrict__ seg1, int n1,
                                              int B, int* __restrict__ cnt0, int* __restrict__ cnt1) {
    const int* seg = blockIdx.x ? seg1 : seg0;
    int n = blockIdx.x ? n1 : n0;
    int* cnt = blockIdx.x ? cnt1 : cnt0;
    __shared__ int bound[129];
    int b = threadIdx.x;
    if (b <= B) {
        int lo = 0, hi = n;
        while (lo < hi) {
            int mid = (lo + hi) >> 1;
            if (seg[mid] < b) lo = mid + 1; else hi = mid;
        }
        bound[b] = lo;
    }
    __syncthreads();
    if (b < B) cnt[b] = bound[b + 1] - bound[b];
}

// ---------------- scan (exclusive), both arrays in one grid ----------------
__global__ __launch_bounds__(256) void scan_block2_k(const int* __restrict__ inA, int* __restrict__ outA, int nA, int nbA,
                                                     const int* __restrict__ inB, int* __restrict__ outB, int nB,
                                                     int* __restrict__ bsum) {
    __shared__ int sh[256];
    const int* in; int* out; int n; int gid; int bs;
    if ((int)blockIdx.x < nbA) { in = inA; out = outA; n = nA; gid = blockIdx.x * 256 + threadIdx.x; bs = blockIdx.x; }
    else { in = inB; out = outB; n = nB; gid = (blockIdx.x - nbA) * 256 + threadIdx.x; bs = blockIdx.x; }
    int v = (gid < n) ? in[gid] : 0;
    sh[threadIdx.x] = v;
    __syncthreads();
    for (int off = 1; off < 256; off <<= 1) {
        int t = (threadIdx.x >= off) ? sh[threadIdx.x - off] : 0;
        __syncthreads();
        sh[threadIdx.x] += t;
        __syncthreads();
    }
    if (gid < n) out[gid] = sh[threadIdx.x] - v;
    if (threadIdx.x == 255) bsum[bs] = sh[255];
}

__global__ __launch_bounds__(256) void scan_bsum2_k(int* __restrict__ bsum, int nbA, int nbB) {
    __shared__ int sh[256];
    __shared__ int carry;
#pragma unroll 1
    for (int part = 0; part < 2; ++part) {
        int base0 = part ? nbA : 0;
        int nb = part ? nbB : nbA;
        if (threadIdx.x == 0) carry = 0;
        __syncthreads();
        for (int base = 0; base < nb; base += 256) {
            int i = base + threadIdx.x;
            int v = (i < nb) ? bsum[base0 + i] : 0;
            sh[threadIdx.x] = v;
            __syncthreads();
            for (int off = 1; off < 256; off <<= 1) {
                int t = (threadIdx.x >= off) ? sh[threadIdx.x - off] : 0;
                __syncthreads();
                sh[threadIdx.x] += t;
                __syncthreads();
            }
            if (i < nb) bsum[base0 + i] = sh[threadIdx.x] - v + carry;
            __syncthreads();
            if (threadIdx.x == 0) carry += sh[255];
            __syncthreads();
        }
    }
}

__global__ __launch_bounds__(256) void scan_add2_k(int* __restrict__ offsA, int* __restrict__ curA, int nA, int nbA, int nnzA,
                                                   int* __restrict__ offsB, int* __restrict__ curB, int nB, int nnzB,
                                                   const int* __restrict__ bsum) {
    int* offs; int* curp; int n; int gid; int bs; int nnz;
    if ((int)blockIdx.x < nbA) { offs = offsA; curp = curA; n = nA; gid = blockIdx.x * 256 + threadIdx.x; bs = blockIdx.x; nnz = nnzA; }
    else { offs = offsB; curp = curB; n = nB; gid = (blockIdx.x - nbA) * 256 + threadIdx.x; bs = blockIdx.x; nnz = nnzB; }
    if (gid < n) {
        int v = offs[gid] + bsum[bs];
        offs[gid] = v;
        curp[gid] = v;
    }
    if (gid == 0) offs[n] = nnz;
}

// ---------------- CSR fill (both graphs): slot gets (src, dst) pair ----------------
__global__ __launch_bounds__(256) void fill2_k(const int* __restrict__ src, const int* __restrict__ dst,
                                               const int* __restrict__ lsrc, const int* __restrict__ ldst,
                                               int* __restrict__ cur_n, int* __restrict__ cur_e,
                                               uint2* __restrict__ nbr_n, uint2* __restrict__ nbr_e,
                                               int E, int E2) {
    int i = blockIdx.x * 256 + threadIdx.x;
    if (i < E) {
        int dd = dst[i];
        int p = atomicAdd(&cur_n[dd], 1);
        nbr_n[p] = make_uint2((u32)src[i], (u32)dd);
    } else if (i < E + E2) {
        int j = i - E;
        int dd = ldst[j];
        int p = atomicAdd(&cur_e[dd], 1);
        nbr_e[p] = make_uint2((u32)lsrc[j], (u32)dd);
    }
}

// ---------------- weight prep (all 6): Wt[n][k] = (f16) W[k][n] ----------------
__global__ __launch_bounds__(256) void prep_w_all_k(const float* __restrict__ gW, const float* __restrict__ lgW,
                                                    f16* __restrict__ wt, int L) {
    int mat = blockIdx.x >> 6;
    int idx = (blockIdx.x & 63) * 256 + threadIdx.x;
    int k = idx >> 7, n = idx & 127;
    const float* W = (mat < L) ? gW + (size_t)mat * H * H : lgW + (size_t)(mat - L) * H * H;
    wt[(size_t)mat * H * H + (size_t)n * H + k] = (f16)W[(size_t)k * H + n];
}

// ---------------- node feature init (fp8, pre-scaled by rs_out) ----------------
__global__ __launch_bounds__(256) void init_node_k(const int* __restrict__ z, const float* __restrict__ emb,
                                                   const float* __restrict__ ron, u8* __restrict__ featN, int N) {
    int idx = blockIdx.x * 256 + threadIdx.x;
    if (idx >= N * 32) return;
    int n = idx >> 5, c4 = (idx & 31) << 2;
    float sc = ron[n];
    const float4 v = *(const float4*)(emb + (size_t)z[n] * H + c4);
    *(u32*)(featN + (size_t)n * H + c4) = enc4(v.x * sc, v.y * sc, v.z * sc, v.w * sc);
}

// ---------------- MFMA phase: LDS-staged fp8 output; optional full-line global store ----------------
template <bool STORE>
__device__ __forceinline__ void conv_mfma_phase(
    u8* __restrict__ Xout, const f16* __restrict__ Wt, const float* __restrict__ bias,
    const float* __restrict__ scale_out, int M, int row0, f16 (*As)[136], int wave, int lane) {
    const int rowbase = row0 + wave * 16;
    if (rowbase >= M) return;
    const int l15 = lane & 15;
    const int quad = lane >> 4;

    f16x8 a[4];
#pragma unroll
    for (int kt = 0; kt < 4; ++kt)
        a[kt] = *(const f16x8*)&As[wave * 16 + l15][kt * 32 + quad * 8];

    float rsc[4];
#pragma unroll
    for (int r = 0; r < 4; ++r) {
        int gr = rowbase + quad * 4 + r;
        rsc[r] = (scale_out && gr < M) ? scale_out[gr] : 1.f;
    }

    u8* stage = (u8*)&As[wave * 16][0];   // wave-private slice; 16*SSTRIDE=2304B <= 4352B

#pragma unroll
    for (int n0 = 0; n0 < 8; ++n0) {
        f32x4 acc = {0.f, 0.f, 0.f, 0.f};
        const f16* bp = Wt + (size_t)(n0 * 16 + l15) * H + quad * 8;
#pragma unroll
        for (int kt = 0; kt < 4; ++kt) {
            f16x8 b = *(const f16x8*)(bp + kt * 32);
            acc = __builtin_amdgcn_mfma_f32_16x16x32_f16(a[kt], b, acc, 0, 0, 0);
        }
        int col = n0 * 16 + l15;
        float bv = bias[col];
        float o[4];
#pragma unroll
        for (int r = 0; r < 4; ++r) o[r] = fmaxf(acc[r] + bv, 0.f) * rsc[r];
        u32 w = enc4(o[0], o[1], o[2], o[3]);
#pragma unroll
        for (int r = 0; r < 4; ++r) stage[(quad * 4 + r) * SSTRIDE + col] = (u8)(w >> (8 * r));
    }
    if (STORE) {
        // 4 lanes cover one full 128B row => no write-allocate RMW
        const int lr = lane >> 2;
        const int lc = (lane & 3) * 32;
        int gr = rowbase + lr;
        if (gr < M) {
            uint4 v0 = *(const uint4*)&stage[lr * SSTRIDE + lc];
            uint4 v1 = *(const uint4*)&stage[lr * SSTRIDE + lc + 16];
            *(uint4*)(Xout + (size_t)gr * H + lc) = v0;
            *(uint4*)(Xout + (size_t)gr * H + lc + 16) = v1;
        }
    }
}

template <bool STORE>
__device__ __forceinline__ void conv_wave(
    const u8* __restrict__ Xin, u8* __restrict__ Xout,
    const int* __restrict__ offs, const uint2* __restrict__ nbr2,
    const float* __restrict__ rs_in, const f16* __restrict__ Wt,
    const float* __restrict__ bias, const float* __restrict__ scale_out, int M,
    int row0, f16 (*As)[136], int wave, int lane) {
    const int rowbase = row0 + wave * 16;     // wave-private 16 rows

    // zero this wave's As slice
    {
        uint2* zp = (uint2*)&As[wave * 16][0];
#pragma unroll
        for (int i = 0; i < 9; ++i) {
            int o = lane + i * 64;
            if (o < 544) zp[o] = make_uint2(0u, 0u);
        }
    }

    // ---- gather (wave-private) ----
    {
        const int gl = lane >> 4;
        const int ln = lane & 15;
        const int r_lo = min(rowbase + gl * 4, M);
        const int r_hi = min(rowbase + gl * 4 + 4, M);
        const int jbeg = offs[r_lo];
        const int jend = offs[r_hi];
        if (jbeg < jend) {
            float a0 = 0.f, a1 = 0.f, a2 = 0.f, a3 = 0.f, a4 = 0.f, a5 = 0.f, a6 = 0.f, a7 = 0.f;
            int curdst = -1;
            for (int j = jbeg; j < jend; j += 4) {
                int j1 = min(j + 1, jend - 1), j2 = min(j + 2, jend - 1), j3 = min(j + 3, jend - 1);
                uint2 e0 = nbr2[j], e1 = nbr2[j1], e2 = nbr2[j2], e3 = nbr2[j3];
                uint2 f0 = *(const uint2*)(Xin + ((size_t)e0.x << 7) + (ln << 3));
                uint2 f1 = *(const uint2*)(Xin + ((size_t)e1.x << 7) + (ln << 3));
                uint2 f2 = *(const uint2*)(Xin + ((size_t)e2.x << 7) + (ln << 3));
                uint2 f3 = *(const uint2*)(Xin + ((size_t)e3.x << 7) + (ln << 3));
                uint2 ev[4] = {e0, e1, e2, e3};
                uint2 fv[4] = {f0, f1, f2, f3};
#pragma unroll
                for (int k = 0; k < 4; ++k) {
                    if (j + k < jend) {
                        int dk = (int)ev[k].y;
                        if (dk != curdst) {
                            if (curdst >= 0) {
                                float ri = rs_in[curdst];
                                f16x8 o;
                                o[0] = (f16)(a0 * ri); o[1] = (f16)(a1 * ri);
                                o[2] = (f16)(a2 * ri); o[3] = (f16)(a3 * ri);
                                o[4] = (f16)(a4 * ri); o[5] = (f16)(a5 * ri);
                                o[6] = (f16)(a6 * ri); o[7] = (f16)(a7 * ri);
                                *(f16x8*)&As[curdst - row0][ln << 3] = o;
                                a0 = a1 = a2 = a3 = a4 = a5 = a6 = a7 = 0.f;
                            }
                            curdst = dk;
                        }
                        float4 lo = dec4(fv[k].x);
                        float4 hi = dec4(fv[k].y);
                        a0 += lo.x; a1 += lo.y; a2 += lo.z; a3 += lo.w;
                        a4 += hi.x; a5 += hi.y; a6 += hi.z; a7 += hi.w;
                    }
                }
            }
            if (curdst >= 0) {
                float ri = rs_in[curdst];
                f16x8 o;
                o[0] = (f16)(a0 * ri); o[1] = (f16)(a1 * ri);
                o[2] = (f16)(a2 * ri); o[3] = (f16)(a3 * ri);
                o[4] = (f16)(a4 * ri); o[5] = (f16)(a5 * ri);
                o[6] = (f16)(a6 * ri); o[7] = (f16)(a7 * ri);
                *(f16x8*)&As[curdst - row0][ln << 3] = o;
            }
        }
    }
    // no __syncthreads: As slice is wave-private

    conv_mfma_phase<STORE>(Xout, Wt, bias, scale_out, M, row0, As, wave, lane);
}

// ---------------- layer-0 line conv wave: rank-1 features -> 8B scalar gather ----------------
__device__ __forceinline__ void conv_wave_l0e(
    u8* __restrict__ Xout, const int* __restrict__ offs, const uint2* __restrict__ nbr2,
    const float2* __restrict__ pairE, const float* __restrict__ rs_in,
    const float* __restrict__ epw, const float* __restrict__ epb,
    const f16* __restrict__ Wt, const float* __restrict__ bias,
    const float* __restrict__ scale_out, int E,
    int row0, f16 (*As)[136], int wave, int lane) {
    const int rowbase = row0 + wave * 16;
    const int r = lane >> 2;
    const int t = lane & 3;
    int grow = min(rowbase + r, E - 1);
    int jb = offs[grow], je = offs[grow + 1];
    float sd = 0.f, sw = 0.f;
    for (int j = jb + t; j < je; j += 4) {
        float2 p = pairE[nbr2[j].x];
        sd += p.x; sw += p.y;
    }
    sd += __shfl_xor(sd, 1); sw += __shfl_xor(sw, 1);
    sd += __shfl_xor(sd, 2); sw += __shfl_xor(sw, 2);
    float ri = (rowbase + r < E) ? rs_in[rowbase + r] : 0.f;
    sd *= ri; sw *= ri;
#pragma unroll
    for (int c8 = 0; c8 < 4; ++c8) {
        int c0 = t * 32 + c8 * 8;
        const float4 wa = *(const float4*)(epw + c0);
        const float4 wb = *(const float4*)(epw + c0 + 4);
        const float4 ba = *(const float4*)(epb + c0);
        const float4 bb = *(const float4*)(epb + c0 + 4);
        f16x8 o;
        o[0] = (f16)(sd * wa.x + sw * ba.x); o[1] = (f16)(sd * wa.y + sw * ba.y);
        o[2] = (f16)(sd * wa.z + sw * ba.z); o[3] = (f16)(sd * wa.w + sw * ba.w);
        o[4] = (f16)(sd * wb.x + sw * bb.x); o[5] = (f16)(sd * wb.y + sw * bb.y);
        o[6] = (f16)(sd * wb.z + sw * bb.z); o[7] = (f16)(sd * wb.w + sw * bb.w);
        *(f16x8*)&As[wave * 16 + r][c0] = o;
    }
    conv_mfma_phase<true>(Xout, Wt, bias, scale_out, E, row0, As, wave, lane);
}

// ---------------- combined conv (middle layers): node ++ line in one dispatch ----------------
__global__ __launch_bounds__(256) void conv2_k(
    const u8* __restrict__ XinN, u8* __restrict__ XoutN,
    const int* __restrict__ offs_n, const uint2* __restrict__ nbr_n,
    const float* __restrict__ rinN, const f16* __restrict__ WtN,
    const float* __restrict__ biasN, const float* __restrict__ scaleN, int N, int nbCN,
    const u8* __restrict__ XinE, u8* __restrict__ XoutE,
    const int* __restrict__ offs_e, const uint2* __restrict__ nbr_e,
    const float* __restrict__ rinE, const f16* __restrict__ WtE,
    const float* __restrict__ biasE, const float* __restrict__ scaleE, int E) {
    __shared__ f16 As[64][136];
    const int tid = threadIdx.x;
    const int wave = tid >> 6;
    const int lane = tid & 63;
    if ((int)blockIdx.x < nbCN) {
        conv_wave<true>(XinN, XoutN, offs_n, nbr_n, rinN, WtN, biasN, scaleN, N,
                        blockIdx.x * 64, As, wave, lane);
    } else {
        conv_wave<true>(XinE, XoutE, offs_e, nbr_e, rinE, WtE, biasE, scaleE, E,
                        (blockIdx.x - nbCN) * 64, As, wave, lane);
    }
}

// ---------------- combined conv layer 0: node standard ++ line rank-1 ----------------
__global__ __launch_bounds__(256) void conv2_l0_k(
    const u8* __restrict__ XinN, u8* __restrict__ XoutN,
    const int* __restrict__ offs_n, const uint2* __restrict__ nbr_n,
    const float* __restrict__ rinN, const f16* __restrict__ WtN,
    const float* __restrict__ biasN, const float* __restrict__ scaleN, int N, int nbCN,
    u8* __restrict__ XoutE,
    const int* __restrict__ offs_e, const uint2* __restrict__ nbr_e,
    const float2* __restrict__ pairE, const float* __restrict__ rinE,
    const float* __restrict__ epw, const float* __restrict__ epb,
    const f16* __restrict__ WtE, const float* __restrict__ biasE,
    const float* __restrict__ scaleE, int E) {
    __shared__ f16 As[64][136];
    const int tid = threadIdx.x;
    const int wave = tid >> 6;
    const int lane = tid & 63;
    if ((int)blockIdx.x < nbCN) {
        conv_wave<true>(XinN, XoutN, offs_n, nbr_n, rinN, WtN, biasN, scaleN, N,
                        blockIdx.x * 64, As, wave, lane);
    } else {
        conv_wave_l0e(XoutE, offs_e, nbr_e, pairE, rinE, epw, epb, WtE, biasE, scaleE, E,
                      (blockIdx.x - nbCN) * 64, As, wave, lane);
    }
}

// ---------------- final conv layer: conv (stage-only) + fused block pooling ----------------
// Output of the last layer is consumed only by segment-mean pooling -> never write feat to
// global. Stage fp8 in LDS, one barrier, then block-pool the 64x128 tile into hg/he with
// run-length-flushed atomics (64 sorted rows -> ~1-2 graphs/block).
__global__ __launch_bounds__(256) void conv2_last_k(
    const u8* __restrict__ XinN,
    const int* __restrict__ offs_n, const uint2* __restrict__ nbr_n,
    const float* __restrict__ rinN, const f16* __restrict__ WtN,
    const float* __restrict__ biasN, int N, int nbCN,
    const int* __restrict__ node_graph, float* __restrict__ hg,
    const u8* __restrict__ XinE,
    const int* __restrict__ offs_e, const uint2* __restrict__ nbr_e,
    const float* __restrict__ rinE, const f16* __restrict__ WtE,
    const float* __restrict__ biasE, int E,
    const int* __restrict__ edge_graph, float* __restrict__ he) {
    __shared__ f16 As[64][136];
    __shared__ int sgid[64];
    const int tid = threadIdx.x;
    const int wave = tid >> 6;
    const int lane = tid & 63;
    const bool isN = (int)blockIdx.x < nbCN;
    const int row0 = (isN ? blockIdx.x : blockIdx.x - nbCN) * 64;
    const int M = isN ? N : E;
    const int* seg = isN ? node_graph : edge_graph;
    float* outp = isN ? hg : he;

    if (tid < 64) {
        int gr = row0 + tid;
        sgid[tid] = (gr < M) ? seg[gr] : -1;
    }

    if (isN) {
        conv_wave<false>(XinN, nullptr, offs_n, nbr_n, rinN, WtN, biasN, nullptr, N,
                         row0, As, wave, lane);
    } else {
        conv_wave<false>(XinE, nullptr, offs_e, nbr_e, rinE, WtE, biasE, nullptr, E,
                         row0, As, wave, lane);
    }
    __syncthreads();

    // pool: 256 threads -> column j = tid&127, row half = tid>>7 (rows 32*half..+31)
    const int j = tid & 127;
    const int rbeg = (tid >> 7) * 32;
    const u8* sbase = (const u8*)&As[0][0];
    float acc = 0.f;
    int gcur = -1;
    for (int r = rbeg; r < rbeg + 32; ++r) {
        int g = sgid[r];
        if (g < 0) break;   // rows beyond M are only at the tail
        if (g != gcur) {
            if (gcur >= 0) atomicAdd(&outp[(size_t)gcur * H + j], acc);
            acc = 0.f;
            gcur = g;
        }
        acc += dec1(sbase[(size_t)(r >> 4) * (16 * 136 * 2) + (r & 15) * SSTRIDE + j]);
    }
    if (gcur >= 0) atomicAdd(&outp[(size_t)gcur * H + j], acc);
}

// ---------------- readout MLP ----------------
__global__ __launch_bounds__(128) void readout_k(const float* __restrict__ hg, const float* __restrict__ he,
                                                 const int* __restrict__ cn, const int* __restrict__ ce,
                                                 const float* __restrict__ r1w, const float* __restrict__ r1b,
                                                 const float* __restrict__ r2w, const float* __restrict__ r2b,
                                                 float* __restrict__ out) {
    const int b = blockIdx.x;
    const int j = threadIdx.x;
    const float invn = 1.f / fmaxf((float)cn[b], 1.f);
    const float inve = 1.f / fmaxf((float)ce[b], 1.f);
    float acc = r1b[j];
    for (int k = 0; k < H; ++k) acc = fmaf(hg[(size_t)b * H + k] * invn, r1w[(size_t)k * H + j], acc);
    for (int k = 0; k < H; ++k) acc = fmaf(he[(size_t)b * H + k] * inve, r1w[(size_t)(k + H) * H + j], acc);
    float s = acc / (1.f + expf(-acc));
    __shared__ float red[128];
    red[j] = s * r2w[j];
    __syncthreads();
    for (int off = 64; off > 0; off >>= 1) {
        if (j < off) red[j] += red[j + off];
        __syncthreads();
    }
    if (j == 0) out[b] = red[0] + r2b[0];
}

// diagnostic
__global__ void report_k(float* out, int n, float val) {
    int i = blockIdx.x * 64 + threadIdx.x;
    if (i < n) out[i] = val;
}

extern "C" void kernel_launch(void* const* d_in, const int* in_sizes, int n_in,
                              void* d_out, int out_size, void* d_ws, size_t ws_size,
                              hipStream_t stream) {
    const int* z          = (const int*)d_in[0];
    const float* d        = (const float*)d_in[1];
    const int* src        = (const int*)d_in[2];
    const int* dst        = (const int*)d_in[3];
    const int* lsrc       = (const int*)d_in[4];
    const int* ldst       = (const int*)d_in[5];
    const int* node_graph = (const int*)d_in[6];
    const int* edge_graph = (const int*)d_in[7];
    const float* emb      = (const float*)d_in[8];
    const float* epw      = (const float*)d_in[9];
    const float* epb      = (const float*)d_in[10];
    const float* gW       = (const float*)d_in[11];
    const float* gb       = (const float*)d_in[12];
    const float* lgW      = (const float*)d_in[13];
    const float* lgb      = (const float*)d_in[14];
    const float* r1w      = (const float*)d_in[15];
    const float* r1b      = (const float*)d_in[16];
    const float* r2w      = (const float*)d_in[17];
    const float* r2b      = (const float*)d_in[18];

    const int N  = in_sizes[0];
    const int E  = in_sizes[2];
    const int E2 = in_sizes[4];
    const int B  = out_size;
    const int L  = 3;
    float* out = (float*)d_out;
    char* ws = (char*)d_ws;

    // ---- workspace (~219 MB; budget 268 MB) ----
    size_t off = 0;
    auto al = [&](size_t b) -> char* { char* q = ws + off; off += (b + 255) & ~(size_t)255; return q; };
    u8*  featEA = (u8*)al((size_t)E * H);
    u8*  featEB = (u8*)al((size_t)E * H);
    u8*  featNA = (u8*)al((size_t)N * H);
    u8*  featNB = (u8*)al((size_t)N * H);
    f16* wt    = (f16*)al((size_t)2 * L * H * H * 2);
    float* ron = (float*)al((size_t)N * 4);
    float* rin = (float*)al((size_t)N * 4);
    float* roe = (float*)al((size_t)E * 4);
    float* rie = (float*)al((size_t)E * 4);
    float2* pairE = (float2*)al((size_t)E * 8);
    size_t cntCount = (size_t)2 * N + 2 * E + 2 * B;
    int* cnts = (int*)al(cntCount * 4);
    size_t cntBytes = ((size_t)2 * N + 2 * E) * 4;
    int* con = cnts; int* cin_ = con + N; int* coe = cin_ + N; int* cie = coe + E;
    int* cntn = cie + E; int* cnte = cntn + B;
    int* offs_n = (int*)al(((size_t)N + 1) * 4);
    int* cur_n  = (int*)al((size_t)N * 4);
    int* offs_e = (int*)al(((size_t)E + 1) * 4);
    int* cur_e  = (int*)al((size_t)E * 4);
    uint2* nbr_n = (uint2*)al((size_t)E * 8);
    uint2* nbr_e = (uint2*)al((size_t)E2 * 8);
    int nbN = cdiv(N, 256), nbE = cdiv(E, 256);
    int* bsum   = (int*)al(((size_t)nbN + nbE + 2) * 4);
    float* pools = (float*)al((size_t)2 * B * H * 4);
    float* hg = pools;
    float* he = pools + (size_t)B * H;

    if (off > ws_size) {
        report_k<<<cdiv(B, 64), 64, 0, stream>>>(out, B, (float)(ws_size >> 20));
        return;
    }

    hipMemsetAsync(cnts, 0, cntBytes, stream);
    hipMemsetAsync(pools, 0, (size_t)2 * B * H * 4, stream);

    // setup (fused)
    prep_w_all_k<<<2 * L * 64, 256, 0, stream>>>(gW, lgW, wt, L);
    hist_all_k<<<cdiv((long long)E + E2, 256), 256, 0, stream>>>(src, dst, lsrc, ldst, con, cin_, coe, cie, E, E2);
    seg2_k<<<2, 128, 0, stream>>>(node_graph, N, edge_graph, E, B, cntn, cnte);
    rs_all_k<<<cdiv((long long)2 * N + 2 * E, 256), 256, 0, stream>>>(con, cin_, coe, cie, ron, rin, roe, rie,
                                                                     d, pairE, N, E);

    // CSR build (both graphs)
    scan_block2_k<<<nbN + nbE, 256, 0, stream>>>(cin_, offs_n, N, nbN, cie, offs_e, E, bsum);
    scan_bsum2_k<<<1, 256, 0, stream>>>(bsum, nbN, nbE);
    scan_add2_k<<<nbN + nbE, 256, 0, stream>>>(offs_n, cur_n, N, nbN, E, offs_e, cur_e, E, E2, bsum);
    fill2_k<<<cdiv((long long)E + E2, 256), 256, 0, stream>>>(src, dst, lsrc, ldst, cur_n, cur_e, nbr_n, nbr_e, E, E2);

    // node feature init only
    init_node_k<<<cdiv((long long)N * 32, 256), 256, 0, stream>>>(z, emb, ron, featNA, N);

    const int nbCN = cdiv(N, 64), nbCE = cdiv(E, 64);

    // layer 0: node standard ++ line rank-1
    conv2_l0_k<<<nbCN + nbCE, 256, 0, stream>>>(
        featNA, featNB, offs_n, nbr_n, rin, wt, gb, ron, N, nbCN,
        featEB, offs_e, nbr_e, pairE, rie, epw, epb,
        wt + (size_t)L * H * H, lgb, roe, E);

    // layer 1 (middle)
    conv2_k<<<nbCN + nbCE, 256, 0, stream>>>(
        featNB, featNA, offs_n, nbr_n, rin, wt + (size_t)1 * H * H, gb + (size_t)1 * H, ron, N, nbCN,
        featEB, featEA, offs_e, nbr_e, rie, wt + (size_t)(L + 1) * H * H, lgb + (size_t)1 * H, roe, E);

    // layer 2 (final): conv + fused pooling, no global feature write
    conv2_last_k<<<nbCN + nbCE, 256, 0, stream>>>(
        featNA, offs_n, nbr_n, rin, wt + (size_t)2 * H * H, gb + (size_t)2 * H, N, nbCN, node_graph, hg,
        featEA, offs_e, nbr_e, rie, wt + (size_t)(L + 2) * H * H, lgb + (size_t)2 * H, E, edge_graph, he);

    readout_k<<<B, 128, 0, stream>>>(hg, he, cntn, cnte, r1w, r1b, r2w, r2b, out);
}

// Round 16
// 1198.034 us; speedup vs baseline: 1.0930x; 1.0156x over previous
//
#include <hip/hip_runtime.h>
#include <math.h>

#define H 128
typedef unsigned short u16;
typedef unsigned char u8;
typedef unsigned int u32;
typedef _Float16 f16;
typedef f16 f16x8 __attribute__((ext_vector_type(8)));
typedef float f32x4 __attribute__((ext_vector_type(4)));
typedef float f32x2 __attribute__((ext_vector_type(2)));

#if __has_builtin(__builtin_amdgcn_cvt_pk_fp8_f32)
#define HW8 1
#else
#define HW8 0
#endif

#define SSTRIDE 144   // fp8 staging row stride

static inline int cdiv(long long a, long long b) { return (int)((a + b - 1) / b); }

// ---------------- fp8 e4m3fn software codec (fallback) ----------------
struct F8 {
    static __device__ inline float dec(u8 v) {
        int e = (v >> 3) & 15, m = v & 7;
        float f = (e == 0) ? (float)m * 0.001953125f : ldexpf(1.f + 0.125f * (float)m, e - 7);
        return (v & 0x80) ? -f : f;
    }
    static __device__ inline u8 enc(float x) {
        u8 s = (u8)((__float_as_uint(x) >> 24) & 0x80);
        float ax = fabsf(x);
        if (!(ax < 448.f)) return s | 0x7E;
        if (ax < 0.015625f) {
            int m = (int)rintf(ax * 512.f);
            if (m >= 8) return s | 0x08;
            return s | (u8)m;
        }
        int e; float fr = frexpf(ax, &e);
        int E = e - 1;
        int m = (int)rintf(fr * 16.f - 8.f);
        if (m == 8) { m = 0; ++E; }
        if (E > 8) return s | 0x7E;
        return s | (u8)(((E + 7) << 3) | m);
    }
};

static __device__ inline u32 enc4(float x0, float x1, float x2, float x3) {
#if HW8
    u32 w = __builtin_amdgcn_cvt_pk_fp8_f32(x0, x1, 0, false);
    w = __builtin_amdgcn_cvt_pk_fp8_f32(x2, x3, w, true);
    return w;
#else
    union { u8 b[4]; u32 u; } p;
    p.b[0] = F8::enc(x0); p.b[1] = F8::enc(x1); p.b[2] = F8::enc(x2); p.b[3] = F8::enc(x3);
    return p.u;
#endif
}
static __device__ inline float4 dec4(u32 v) {
#if HW8
    f32x2 lo = __builtin_amdgcn_cvt_pk_f32_fp8(v, false);
    f32x2 hi = __builtin_amdgcn_cvt_pk_f32_fp8(v, true);
    return make_float4(lo.x, lo.y, hi.x, hi.y);
#else
    union { u32 u; u8 b[4]; } c; c.u = v;
    return make_float4(F8::dec(c.b[0]), F8::dec(c.b[1]), F8::dec(c.b[2]), F8::dec(c.b[3]));
#endif
}
static __device__ inline float dec1(u8 b) {
#if HW8
    return __builtin_amdgcn_cvt_f32_fp8((int)b, 0);
#else
    return F8::dec(b);
#endif
}

// ---------------- setup1: prep_w ++ hist_all ++ seg2, one dispatch ----------------
__global__ __launch_bounds__(256) void setup1_k(
    const float* __restrict__ gW, const float* __restrict__ lgW, f16* __restrict__ wt, int L, int nbPW,
    const int* __restrict__ src, const int* __restrict__ dst,
    const int* __restrict__ lsrc, const int* __restrict__ ldst,
    int* __restrict__ con, int* __restrict__ cin, int* __restrict__ coe, int* __restrict__ cie,
    int E, int E2, int nbHI,
    const int* __restrict__ node_graph, int N, const int* __restrict__ edge_graph,
    int B, int* __restrict__ cntn, int* __restrict__ cnte) {
    int blk = blockIdx.x;
    if (blk < nbPW) {                       // weight prep
        int mat = blk >> 6;
        int idx = (blk & 63) * 256 + threadIdx.x;
        int k = idx >> 7, n = idx & 127;
        const float* W = (mat < L) ? gW + (size_t)mat * H * H : lgW + (size_t)(mat - L) * H * H;
        wt[(size_t)mat * H * H + (size_t)n * H + k] = (f16)W[(size_t)k * H + n];
        return;
    }
    blk -= nbPW;
    if (blk < nbHI) {                       // degree histograms
        int i = blk * 256 + threadIdx.x;
        if (i < E) {
            atomicAdd(&con[src[i]], 1);
            atomicAdd(&cin[dst[i]], 1);
        } else if (i < E + E2) {
            int j = i - E;
            atomicAdd(&coe[lsrc[j]], 1);
            atomicAdd(&cie[ldst[j]], 1);
        }
        return;
    }
    blk -= nbHI;                            // seg bounds (2 blocks)
    {
        const int* seg = blk ? edge_graph : node_graph;
        int n = blk ? E : N;
        int* cnt = blk ? cnte : cntn;
        __shared__ int bound[129];
        int b = threadIdx.x;
        if (b <= B) {
            int lo = 0, hi = n;
            while (lo < hi) {
                int mid = (lo + hi) >> 1;
                if (seg[mid] < b) lo = mid + 1; else hi = mid;
            }
            bound[b] = lo;
        }
        __syncthreads();
        if (b < B) cnt[b] = bound[b + 1] - bound[b];
    }
}

// ---------------- setup2: rs_all(+pairE) ++ scan_block2, one dispatch ----------------
__global__ __launch_bounds__(256) void setup2_k(
    const int* __restrict__ con, const int* __restrict__ cin,
    const int* __restrict__ coe, const int* __restrict__ cie,
    float* __restrict__ ron, float* __restrict__ rin,
    float* __restrict__ roe, float* __restrict__ rie,
    const float* __restrict__ d, float2* __restrict__ pairE, int N, int E, int nbRS,
    int* __restrict__ offs_n, int nbN, int* __restrict__ offs_e, int* __restrict__ bsum) {
    int blk = blockIdx.x;
    if (blk < nbRS) {                       // rs + pairE
        int i = blk * 256 + threadIdx.x;
        if (i < N) { int v = con[i]; ron[i] = rsqrtf((float)(v < 1 ? 1 : v)); }
        else if (i < 2 * N) { int n = i - N; int v = cin[n]; rin[n] = rsqrtf((float)(v < 1 ? 1 : v)); }
        else if (i < 2 * N + E) {
            int n = i - 2 * N; int v = coe[n];
            float r = rsqrtf((float)(v < 1 ? 1 : v));
            roe[n] = r;
            pairE[n] = make_float2(r * d[n], r);
        } else if (i < 2 * N + 2 * E) {
            int n = i - 2 * N - E; int v = cie[n]; rie[n] = rsqrtf((float)(v < 1 ? 1 : v));
        }
        return;
    }
    blk -= nbRS;                            // block scans (nbN for cin->offs_n, rest cie->offs_e)
    {
        __shared__ int sh[256];
        const int* in; int* out; int n; int gid;
        if (blk < nbN) { in = cin; out = offs_n; n = N; gid = blk * 256 + threadIdx.x; }
        else { in = cie; out = offs_e; n = E; gid = (blk - nbN) * 256 + threadIdx.x; }
        int v = (gid < n) ? in[gid] : 0;
        sh[threadIdx.x] = v;
        __syncthreads();
        for (int off = 1; off < 256; off <<= 1) {
            int t = (threadIdx.x >= off) ? sh[threadIdx.x - off] : 0;
            __syncthreads();
            sh[threadIdx.x] += t;
            __syncthreads();
        }
        if (gid < n) out[gid] = sh[threadIdx.x] - v;
        if (threadIdx.x == 255) bsum[blk] = sh[255];
    }
}

__global__ __launch_bounds__(256) void scan_bsum2_k(int* __restrict__ bsum, int nbA, int nbB) {
    __shared__ int sh[256];
    __shared__ int carry;
#pragma unroll 1
    for (int part = 0; part < 2; ++part) {
        int base0 = part ? nbA : 0;
        int nb = part ? nbB : nbA;
        if (threadIdx.x == 0) carry = 0;
        __syncthreads();
        for (int base = 0; base < nb; base += 256) {
            int i = base + threadIdx.x;
            int v = (i < nb) ? bsum[base0 + i] : 0;
            sh[threadIdx.x] = v;
            __syncthreads();
            for (int off = 1; off < 256; off <<= 1) {
                int t = (threadIdx.x >= off) ? sh[threadIdx.x - off] : 0;
                __syncthreads();
                sh[threadIdx.x] += t;
                __syncthreads();
            }
            if (i < nb) bsum[base0 + i] = sh[threadIdx.x] - v + carry;
            __syncthreads();
            if (threadIdx.x == 0) carry += sh[255];
            __syncthreads();
        }
    }
}

// ---------------- setup3: scan_add2 ++ init_node, one dispatch ----------------
__global__ __launch_bounds__(256) void setup3_k(
    int* __restrict__ offs_n, int* __restrict__ cur_n, int N, int nbN, int E,
    int* __restrict__ offs_e, int* __restrict__ cur_e, int E2, int nbE,
    const int* __restrict__ bsum,
    const int* __restrict__ z, const float* __restrict__ emb,
    const float* __restrict__ ron, u8* __restrict__ featN) {
    int blk = blockIdx.x;
    int nbSA = nbN + nbE;
    if (blk < nbSA) {                       // scan add (offs += bsum; cursor init; tail nnz)
        int* offs; int* curp; int n; int gid; int nnz;
        if (blk < nbN) { offs = offs_n; curp = cur_n; n = N; gid = blk * 256 + threadIdx.x; nnz = E; }
        else { offs = offs_e; curp = cur_e; n = E; gid = (blk - nbN) * 256 + threadIdx.x; nnz = E2; }
        if (gid < n) {
            int v = offs[gid] + bsum[blk];
            offs[gid] = v;
            curp[gid] = v;
        }
        if (gid == 0) offs[n] = nnz;
        return;
    }
    blk -= nbSA;                            // node feature init (fp8, pre-scaled by ron)
    {
        int idx = blk * 256 + threadIdx.x;
        if (idx >= N * 32) return;
        int n = idx >> 5, c4 = (idx & 31) << 2;
        float sc = ron[n];
        const float4 v = *(const float4*)(emb + (size_t)z[n] * H + c4);
        *(u32*)(featN + (size_t)n * H + c4) = enc4(v.x * sc, v.y * sc, v.z * sc, v.w * sc);
    }
}

// ---------------- CSR fill (both graphs): slot gets (src, dst) pair ----------------
__global__ __launch_bounds__(256) void fill2_k(const int* __restrict__ src, const int* __restrict__ dst,
                                               const int* __restrict__ lsrc, const int* __restrict__ ldst,
                                               int* __restrict__ cur_n, int* __restrict__ cur_e,
                                               uint2* __restrict__ nbr_n, uint2* __restrict__ nbr_e,
                                               int E, int E2) {
    int i = blockIdx.x * 256 + threadIdx.x;
    if (i < E) {
        int dd = dst[i];
        int p = atomicAdd(&cur_n[dd], 1);
        nbr_n[p] = make_uint2((u32)src[i], (u32)dd);
    } else if (i < E + E2) {
        int j = i - E;
        int dd = ldst[j];
        int p = atomicAdd(&cur_e[dd], 1);
        nbr_e[p] = make_uint2((u32)lsrc[j], (u32)dd);
    }
}

// ---------------- MFMA phase: LDS-staged fp8 output; optional full-line global store ----------------
template <bool STORE>
__device__ __forceinline__ void conv_mfma_phase(
    u8* __restrict__ Xout, const f16* __restrict__ Wt, const float* __restrict__ bias,
    const float* __restrict__ scale_out, int M, int row0, f16 (*As)[136], int wave, int lane) {
    const int rowbase = row0 + wave * 16;
    if (rowbase >= M) return;
    const int l15 = lane & 15;
    const int quad = lane >> 4;

    f16x8 a[4];
#pragma unroll
    for (int kt = 0; kt < 4; ++kt)
        a[kt] = *(const f16x8*)&As[wave * 16 + l15][kt * 32 + quad * 8];

    float rsc[4];
#pragma unroll
    for (int r = 0; r < 4; ++r) {
        int gr = rowbase + quad * 4 + r;
        rsc[r] = (scale_out && gr < M) ? scale_out[gr] : 1.f;
    }

    u8* stage = (u8*)&As[wave * 16][0];

#pragma unroll
    for (int n0 = 0; n0 < 8; ++n0) {
        f32x4 acc = {0.f, 0.f, 0.f, 0.f};
        const f16* bp = Wt + (size_t)(n0 * 16 + l15) * H + quad * 8;
#pragma unroll
        for (int kt = 0; kt < 4; ++kt) {
            f16x8 b = *(const f16x8*)(bp + kt * 32);
            acc = __builtin_amdgcn_mfma_f32_16x16x32_f16(a[kt], b, acc, 0, 0, 0);
        }
        int col = n0 * 16 + l15;
        float bv = bias[col];
        float o[4];
#pragma unroll
        for (int r = 0; r < 4; ++r) o[r] = fmaxf(acc[r] + bv, 0.f) * rsc[r];
        u32 w = enc4(o[0], o[1], o[2], o[3]);
#pragma unroll
        for (int r = 0; r < 4; ++r) stage[(quad * 4 + r) * SSTRIDE + col] = (u8)(w >> (8 * r));
    }
    if (STORE) {
        const int lr = lane >> 2;
        const int lc = (lane & 3) * 32;
        int gr = rowbase + lr;
        if (gr < M) {
            uint4 v0 = *(const uint4*)&stage[lr * SSTRIDE + lc];
            uint4 v1 = *(const uint4*)&stage[lr * SSTRIDE + lc + 16];
            *(uint4*)(Xout + (size_t)gr * H + lc) = v0;
            *(uint4*)(Xout + (size_t)gr * H + lc + 16) = v1;
        }
    }
}

template <bool STORE>
__device__ __forceinline__ void conv_wave(
    const u8* __restrict__ Xin, u8* __restrict__ Xout,
    const int* __restrict__ offs, const uint2* __restrict__ nbr2,
    const float* __restrict__ rs_in, const f16* __restrict__ Wt,
    const float* __restrict__ bias, const float* __restrict__ scale_out, int M,
    int row0, f16 (*As)[136], int wave, int lane) {
    const int rowbase = row0 + wave * 16;

    {
        uint2* zp = (uint2*)&As[wave * 16][0];
#pragma unroll
        for (int i = 0; i < 9; ++i) {
            int o = lane + i * 64;
            if (o < 544) zp[o] = make_uint2(0u, 0u);
        }
    }

    // ---- gather (wave-private) ----
    {
        const int gl = lane >> 4;
        const int ln = lane & 15;
        const int r_lo = min(rowbase + gl * 4, M);
        const int r_hi = min(rowbase + gl * 4 + 4, M);
        const int jbeg = offs[r_lo];
        const int jend = offs[r_hi];
        if (jbeg < jend) {
            float a0 = 0.f, a1 = 0.f, a2 = 0.f, a3 = 0.f, a4 = 0.f, a5 = 0.f, a6 = 0.f, a7 = 0.f;
            int curdst = -1;
            for (int j = jbeg; j < jend; j += 4) {
                int j1 = min(j + 1, jend - 1), j2 = min(j + 2, jend - 1), j3 = min(j + 3, jend - 1);
                uint2 e0 = nbr2[j], e1 = nbr2[j1], e2 = nbr2[j2], e3 = nbr2[j3];
                uint2 f0 = *(const uint2*)(Xin + ((size_t)e0.x << 7) + (ln << 3));
                uint2 f1 = *(const uint2*)(Xin + ((size_t)e1.x << 7) + (ln << 3));
                uint2 f2 = *(const uint2*)(Xin + ((size_t)e2.x << 7) + (ln << 3));
                uint2 f3 = *(const uint2*)(Xin + ((size_t)e3.x << 7) + (ln << 3));
                uint2 ev[4] = {e0, e1, e2, e3};
                uint2 fv[4] = {f0, f1, f2, f3};
#pragma unroll
                for (int k = 0; k < 4; ++k) {
                    if (j + k < jend) {
                        int dk = (int)ev[k].y;
                        if (dk != curdst) {
                            if (curdst >= 0) {
                                float ri = rs_in[curdst];
                                f16x8 o;
                                o[0] = (f16)(a0 * ri); o[1] = (f16)(a1 * ri);
                                o[2] = (f16)(a2 * ri); o[3] = (f16)(a3 * ri);
                                o[4] = (f16)(a4 * ri); o[5] = (f16)(a5 * ri);
                                o[6] = (f16)(a6 * ri); o[7] = (f16)(a7 * ri);
                                *(f16x8*)&As[curdst - row0][ln << 3] = o;
                                a0 = a1 = a2 = a3 = a4 = a5 = a6 = a7 = 0.f;
                            }
                            curdst = dk;
                        }
                        float4 lo = dec4(fv[k].x);
                        float4 hi = dec4(fv[k].y);
                        a0 += lo.x; a1 += lo.y; a2 += lo.z; a3 += lo.w;
                        a4 += hi.x; a5 += hi.y; a6 += hi.z; a7 += hi.w;
                    }
                }
            }
            if (curdst >= 0) {
                float ri = rs_in[curdst];
                f16x8 o;
                o[0] = (f16)(a0 * ri); o[1] = (f16)(a1 * ri);
                o[2] = (f16)(a2 * ri); o[3] = (f16)(a3 * ri);
                o[4] = (f16)(a4 * ri); o[5] = (f16)(a5 * ri);
                o[6] = (f16)(a6 * ri); o[7] = (f16)(a7 * ri);
                *(f16x8*)&As[curdst - row0][ln << 3] = o;
            }
        }
    }
    // no __syncthreads: As slice is wave-private

    conv_mfma_phase<STORE>(Xout, Wt, bias, scale_out, M, row0, As, wave, lane);
}

// ---------------- layer-0 line conv wave: rank-1 features -> 8B scalar gather ----------------
__device__ __forceinline__ void conv_wave_l0e(
    u8* __restrict__ Xout, const int* __restrict__ offs, const uint2* __restrict__ nbr2,
    const float2* __restrict__ pairE, const float* __restrict__ rs_in,
    const float* __restrict__ epw, const float* __restrict__ epb,
    const f16* __restrict__ Wt, const float* __restrict__ bias,
    const float* __restrict__ scale_out, int E,
    int row0, f16 (*As)[136], int wave, int lane) {
    const int rowbase = row0 + wave * 16;
    const int r = lane >> 2;
    const int t = lane & 3;
    int grow = min(rowbase + r, E - 1);
    int jb = offs[grow], je = offs[grow + 1];
    float sd = 0.f, sw = 0.f;
    for (int j = jb + t; j < je; j += 4) {
        float2 p = pairE[nbr2[j].x];
        sd += p.x; sw += p.y;
    }
    sd += __shfl_xor(sd, 1); sw += __shfl_xor(sw, 1);
    sd += __shfl_xor(sd, 2); sw += __shfl_xor(sw, 2);
    float ri = (rowbase + r < E) ? rs_in[rowbase + r] : 0.f;
    sd *= ri; sw *= ri;
#pragma unroll
    for (int c8 = 0; c8 < 4; ++c8) {
        int c0 = t * 32 + c8 * 8;
        const float4 wa = *(const float4*)(epw + c0);
        const float4 wb = *(const float4*)(epw + c0 + 4);
        const float4 ba = *(const float4*)(epb + c0);
        const float4 bb = *(const float4*)(epb + c0 + 4);
        f16x8 o;
        o[0] = (f16)(sd * wa.x + sw * ba.x); o[1] = (f16)(sd * wa.y + sw * ba.y);
        o[2] = (f16)(sd * wa.z + sw * ba.z); o[3] = (f16)(sd * wa.w + sw * ba.w);
        o[4] = (f16)(sd * wb.x + sw * bb.x); o[5] = (f16)(sd * wb.y + sw * bb.y);
        o[6] = (f16)(sd * wb.z + sw * bb.z); o[7] = (f16)(sd * wb.w + sw * bb.w);
        *(f16x8*)&As[wave * 16 + r][c0] = o;
    }
    conv_mfma_phase<true>(Xout, Wt, bias, scale_out, E, row0, As, wave, lane);
}

// ---------------- combined conv (middle layer): node ++ line in one dispatch ----------------
__global__ __launch_bounds__(256) void conv2_k(
    const u8* __restrict__ XinN, u8* __restrict__ XoutN,
    const int* __restrict__ offs_n, const uint2* __restrict__ nbr_n,
    const float* __restrict__ rinN, const f16* __restrict__ WtN,
    const float* __restrict__ biasN, const float* __restrict__ scaleN, int N, int nbCN,
    const u8* __restrict__ XinE, u8* __restrict__ XoutE,
    const int* __restrict__ offs_e, const uint2* __restrict__ nbr_e,
    const float* __restrict__ rinE, const f16* __restrict__ WtE,
    const float* __restrict__ biasE, const float* __restrict__ scaleE, int E) {
    __shared__ f16 As[64][136];
    const int tid = threadIdx.x;
    const int wave = tid >> 6;
    const int lane = tid & 63;
    if ((int)blockIdx.x < nbCN) {
        conv_wave<true>(XinN, XoutN, offs_n, nbr_n, rinN, WtN, biasN, scaleN, N,
                        blockIdx.x * 64, As, wave, lane);
    } else {
        conv_wave<true>(XinE, XoutE, offs_e, nbr_e, rinE, WtE, biasE, scaleE, E,
                        (blockIdx.x - nbCN) * 64, As, wave, lane);
    }
}

// ---------------- combined conv layer 0: node standard ++ line rank-1 ----------------
__global__ __launch_bounds__(256) void conv2_l0_k(
    const u8* __restrict__ XinN, u8* __restrict__ XoutN,
    const int* __restrict__ offs_n, const uint2* __restrict__ nbr_n,
    const float* __restrict__ rinN, const f16* __restrict__ WtN,
    const float* __restrict__ biasN, const float* __restrict__ scaleN, int N, int nbCN,
    u8* __restrict__ XoutE,
    const int* __restrict__ offs_e, const uint2* __restrict__ nbr_e,
    const float2* __restrict__ pairE, const float* __restrict__ rinE,
    const float* __restrict__ epw, const float* __restrict__ epb,
    const f16* __restrict__ WtE, const float* __restrict__ biasE,
    const float* __restrict__ scaleE, int E) {
    __shared__ f16 As[64][136];
    const int tid = threadIdx.x;
    const int wave = tid >> 6;
    const int lane = tid & 63;
    if ((int)blockIdx.x < nbCN) {
        conv_wave<true>(XinN, XoutN, offs_n, nbr_n, rinN, WtN, biasN, scaleN, N,
                        blockIdx.x * 64, As, wave, lane);
    } else {
        conv_wave_l0e(XoutE, offs_e, nbr_e, pairE, rinE, epw, epb, WtE, biasE, scaleE, E,
                      (blockIdx.x - nbCN) * 64, As, wave, lane);
    }
}

// ---------------- final conv layer: conv (stage-only) + fused block pooling ----------------
__global__ __launch_bounds__(256) void conv2_last_k(
    const u8* __restrict__ XinN,
    const int* __restrict__ offs_n, const uint2* __restrict__ nbr_n,
    const float* __restrict__ rinN, const f16* __restrict__ WtN,
    const float* __restrict__ biasN, int N, int nbCN,
    const int* __restrict__ node_graph, float* __restrict__ hg,
    const u8* __restrict__ XinE,
    const int* __restrict__ offs_e, const uint2* __restrict__ nbr_e,
    const float* __restrict__ rinE, const f16* __restrict__ WtE,
    const float* __restrict__ biasE, int E,
    const int* __restrict__ edge_graph, float* __restrict__ he) {
    __shared__ f16 As[64][136];
    __shared__ int sgid[64];
    const int tid = threadIdx.x;
    const int wave = tid >> 6;
    const int lane = tid & 63;
    const bool isN = (int)blockIdx.x < nbCN;
    const int row0 = (isN ? blockIdx.x : blockIdx.x - nbCN) * 64;
    const int M = isN ? N : E;
    const int* seg = isN ? node_graph : edge_graph;
    float* outp = isN ? hg : he;

    if (tid < 64) {
        int gr = row0 + tid;
        sgid[tid] = (gr < M) ? seg[gr] : -1;
    }

    if (isN) {
        conv_wave<false>(XinN, nullptr, offs_n, nbr_n, rinN, WtN, biasN, nullptr, N,
                         row0, As, wave, lane);
    } else {
        conv_wave<false>(XinE, nullptr, offs_e, nbr_e, rinE, WtE, biasE, nullptr, E,
                         row0, As, wave, lane);
    }
    __syncthreads();

    const int j = tid & 127;
    const int rbeg = (tid >> 7) * 32;
    const u8* sbase = (const u8*)&As[0][0];
    float acc = 0.f;
    int gcur = -1;
    for (int r = rbeg; r < rbeg + 32; ++r) {
        int g = sgid[r];
        if (g < 0) break;
        if (g != gcur) {
            if (gcur >= 0) atomicAdd(&outp[(size_t)gcur * H + j], acc);
            acc = 0.f;
            gcur = g;
        }
        acc += dec1(sbase[(size_t)(r >> 4) * (16 * 136 * 2) + (r & 15) * SSTRIDE + j]);
    }
    if (gcur >= 0) atomicAdd(&outp[(size_t)gcur * H + j], acc);
}

// ---------------- readout MLP ----------------
__global__ __launch_bounds__(128) void readout_k(const float* __restrict__ hg, const float* __restrict__ he,
                                                 const int* __restrict__ cn, const int* __restrict__ ce,
                                                 const float* __restrict__ r1w, const float* __restrict__ r1b,
                                                 const float* __restrict__ r2w, const float* __restrict__ r2b,
                                                 float* __restrict__ out) {
    const int b = blockIdx.x;
    const int j = threadIdx.x;
    const float invn = 1.f / fmaxf((float)cn[b], 1.f);
    const float inve = 1.f / fmaxf((float)ce[b], 1.f);
    float acc = r1b[j];
    for (int k = 0; k < H; ++k) acc = fmaf(hg[(size_t)b * H + k] * invn, r1w[(size_t)k * H + j], acc);
    for (int k = 0; k < H; ++k) acc = fmaf(he[(size_t)b * H + k] * inve, r1w[(size_t)(k + H) * H + j], acc);
    float s = acc / (1.f + expf(-acc));
    __shared__ float red[128];
    red[j] = s * r2w[j];
    __syncthreads();
    for (int off = 64; off > 0; off >>= 1) {
        if (j < off) red[j] += red[j + off];
        __syncthreads();
    }
    if (j == 0) out[b] = red[0] + r2b[0];
}

// diagnostic
__global__ void report_k(float* out, int n, float val) {
    int i = blockIdx.x * 64 + threadIdx.x;
    if (i < n) out[i] = val;
}

extern "C" void kernel_launch(void* const* d_in, const int* in_sizes, int n_in,
                              void* d_out, int out_size, void* d_ws, size_t ws_size,
                              hipStream_t stream) {
    const int* z          = (const int*)d_in[0];
    const float* d        = (const float*)d_in[1];
    const int* src        = (const int*)d_in[2];
    const int* dst        = (const int*)d_in[3];
    const int* lsrc       = (const int*)d_in[4];
    const int* ldst       = (const int*)d_in[5];
    const int* node_graph = (const int*)d_in[6];
    const int* edge_graph = (const int*)d_in[7];
    const float* emb      = (const float*)d_in[8];
    const float* epw      = (const float*)d_in[9];
    const float* epb      = (const float*)d_in[10];
    const float* gW       = (const float*)d_in[11];
    const float* gb       = (const float*)d_in[12];
    const float* lgW      = (const float*)d_in[13];
    const float* lgb      = (const float*)d_in[14];
    const float* r1w      = (const float*)d_in[15];
    const float* r1b      = (const float*)d_in[16];
    const float* r2w      = (const float*)d_in[17];
    const float* r2b      = (const float*)d_in[18];

    const int N  = in_sizes[0];
    const int E  = in_sizes[2];
    const int E2 = in_sizes[4];
    const int B  = out_size;
    const int L  = 3;
    float* out = (float*)d_out;
    char* ws = (char*)d_ws;

    // ---- workspace (~219 MB; budget 268 MB) ----
    size_t off = 0;
    auto al = [&](size_t b) -> char* { char* q = ws + off; off += (b + 255) & ~(size_t)255; return q; };
    u8*  featEA = (u8*)al((size_t)E * H);
    u8*  featEB = (u8*)al((size_t)E * H);
    u8*  featNA = (u8*)al((size_t)N * H);
    u8*  featNB = (u8*)al((size_t)N * H);
    f16* wt    = (f16*)al((size_t)2 * L * H * H * 2);
    float* ron = (float*)al((size_t)N * 4);
    float* rin = (float*)al((size_t)N * 4);
    float* roe = (float*)al((size_t)E * 4);
    float* rie = (float*)al((size_t)E * 4);
    float2* pairE = (float2*)al((size_t)E * 8);
    // cnts + pools in ONE allocation so one memset covers both
    size_t cntCount = (size_t)2 * N + 2 * E + 2 * B;
    size_t cntBytes = cntCount * 4;
    size_t poolsOff = (cntBytes + 255) & ~(size_t)255;
    char* zblock = al(poolsOff + (size_t)2 * B * H * 4);
    int* cnts = (int*)zblock;
    float* pools = (float*)(zblock + poolsOff);
    int* con = cnts; int* cin_ = con + N; int* coe = cin_ + N; int* cie = coe + E;
    int* cntn = cie + E; int* cnte = cntn + B;
    float* hg = pools;
    float* he = pools + (size_t)B * H;
    int* offs_n = (int*)al(((size_t)N + 1) * 4);
    int* cur_n  = (int*)al((size_t)N * 4);
    int* offs_e = (int*)al(((size_t)E + 1) * 4);
    int* cur_e  = (int*)al((size_t)E * 4);
    uint2* nbr_n = (uint2*)al((size_t)E * 8);
    uint2* nbr_e = (uint2*)al((size_t)E2 * 8);
    int nbN = cdiv(N, 256), nbE = cdiv(E, 256);
    int* bsum   = (int*)al(((size_t)nbN + nbE + 2) * 4);

    if (off > ws_size) {
        report_k<<<cdiv(B, 64), 64, 0, stream>>>(out, B, (float)(ws_size >> 20));
        return;
    }

    // one memset: degree counters + (cntn/cnte, overwritten later, harmless) + pools
    hipMemsetAsync(zblock, 0, poolsOff + (size_t)2 * B * H * 4, stream);

    // setup1: prep_w ++ hist ++ seg bounds
    const int nbPW = 2 * L * 64;
    const int nbHI = cdiv((long long)E + E2, 256);
    setup1_k<<<nbPW + nbHI + 2, 256, 0, stream>>>(gW, lgW, wt, L, nbPW,
                                                  src, dst, lsrc, ldst, con, cin_, coe, cie,
                                                  E, E2, nbHI, node_graph, N, edge_graph, B, cntn, cnte);

    // setup2: rs(+pairE) ++ block scans
    const int nbRS = cdiv((long long)2 * N + 2 * E, 256);
    setup2_k<<<nbRS + nbN + nbE, 256, 0, stream>>>(con, cin_, coe, cie, ron, rin, roe, rie,
                                                   d, pairE, N, E, nbRS, offs_n, nbN, offs_e, bsum);
    scan_bsum2_k<<<1, 256, 0, stream>>>(bsum, nbN, nbE);

    // setup3: scan add ++ node feature init
    const int nbIN = cdiv((long long)N * 32, 256);
    setup3_k<<<nbN + nbE + nbIN, 256, 0, stream>>>(offs_n, cur_n, N, nbN, E,
                                                   offs_e, cur_e, E2, nbE, bsum, z, emb, ron, featNA);

    // CSR fill (both graphs)
    fill2_k<<<cdiv((long long)E + E2, 256), 256, 0, stream>>>(src, dst, lsrc, ldst, cur_n, cur_e, nbr_n, nbr_e, E, E2);

    const int nbCN = cdiv(N, 64), nbCE = cdiv(E, 64);

    // layer 0: node standard ++ line rank-1
    conv2_l0_k<<<nbCN + nbCE, 256, 0, stream>>>(
        featNA, featNB, offs_n, nbr_n, rin, wt, gb, ron, N, nbCN,
        featEB, offs_e, nbr_e, pairE, rie, epw, epb,
        wt + (size_t)L * H * H, lgb, roe, E);

    // layer 1 (middle)
    conv2_k<<<nbCN + nbCE, 256, 0, stream>>>(
        featNB, featNA, offs_n, nbr_n, rin, wt + (size_t)1 * H * H, gb + (size_t)1 * H, ron, N, nbCN,
        featEB, featEA, offs_e, nbr_e, rie, wt + (size_t)(L + 1) * H * H, lgb + (size_t)1 * H, roe, E);

    // layer 2 (final): conv + fused pooling
    conv2_last_k<<<nbCN + nbCE, 256, 0, stream>>>(
        featNA, offs_n, nbr_n, rin, wt + (size_t)2 * H * H, gb + (size_t)2 * H, N, nbCN, node_graph, hg,
        featEA, offs_e, nbr_e, rie, wt + (size_t)(L + 2) * H * H, lgb + (size_t)2 * H, E, edge_graph, he);

    readout_k<<<B, 128, 0, stream>>>(hg, he, cntn, cnte, r1w, r1b, r2w, r2b, out);
}